// Round 1
// baseline (805.307 us; speedup 1.0000x reference)
//
#include <hip/hip_runtime.h>
#include <math.h>

#define NNODES 50000
#define FIN 512
#define HID 64
#define HEADS 4
#define HD (HEADS * HID)   // 256
#define NCLS 40
#define NEG_SLOPE 0.2f

// ---------------- GEMM1: h1[N,256] = x[N,512] @ W1[512,256] (fp32) -----------
#define TM 128
#define TN 64
#define TK 16

__global__ __launch_bounds__(256) void gemm1_kernel(const float* __restrict__ x,
                                                    const float* __restrict__ W,
                                                    float* __restrict__ h1) {
    __shared__ float As[TK][132];  // [k][m], padded to dodge 4-way store conflicts
    __shared__ float Bs[TK][TN];
    const int m0 = blockIdx.x * TM;
    const int n0 = blockIdx.y * TN;
    const int tid = threadIdx.x;
    const int tx = tid & 15;       // 0..15 -> 4 cols each
    const int ty = tid >> 4;       // 0..15 -> 8 rows each
    float acc[8][4] = {};

    for (int k0 = 0; k0 < FIN; k0 += TK) {
        // A tile: 128 rows x 16 k  (2 float4 per thread)
        {
            const int r = tid >> 2;            // 0..63
            const int kq = (tid & 3) * 4;      // 0,4,8,12
            #pragma unroll
            for (int rr = 0; rr < 2; ++rr) {
                const int row = r + rr * 64;
                const int gm = m0 + row;
                float4 v = make_float4(0.f, 0.f, 0.f, 0.f);
                if (gm < NNODES)
                    v = *(const float4*)&x[(size_t)gm * FIN + k0 + kq];
                As[kq + 0][row] = v.x;
                As[kq + 1][row] = v.y;
                As[kq + 2][row] = v.z;
                As[kq + 3][row] = v.w;
            }
        }
        // B tile: 16 k x 64 cols (1 float4 per thread)
        {
            const int kr = tid >> 4;           // 0..15
            const int cg = (tid & 15) * 4;
            *(float4*)&Bs[kr][cg] = *(const float4*)&W[(size_t)(k0 + kr) * HD + n0 + cg];
        }
        __syncthreads();
        #pragma unroll
        for (int kk = 0; kk < TK; ++kk) {
            float a[8], b[4];
            #pragma unroll
            for (int i = 0; i < 8; ++i) a[i] = As[kk][ty * 8 + i];
            #pragma unroll
            for (int j = 0; j < 4; ++j) b[j] = Bs[kk][tx * 4 + j];
            #pragma unroll
            for (int i = 0; i < 8; ++i)
                #pragma unroll
                for (int j = 0; j < 4; ++j)
                    acc[i][j] = fmaf(a[i], b[j], acc[i][j]);
        }
        __syncthreads();
    }
    #pragma unroll
    for (int i = 0; i < 8; ++i) {
        const int gm = m0 + ty * 8 + i;
        if (gm < NNODES) {
            float4 v = make_float4(acc[i][0], acc[i][1], acc[i][2], acc[i][3]);
            *(float4*)&h1[(size_t)gm * HD + n0 + tx * 4] = v;
        }
    }
}

// ---------------- per-node attention scores for layer 1 ----------------------
__global__ __launch_bounds__(256) void al1_kernel(const float* __restrict__ h1,
                                                  const float* __restrict__ a_src,
                                                  const float* __restrict__ a_dst,
                                                  float* __restrict__ al_s,
                                                  float* __restrict__ al_d) {
    const int node = (blockIdx.x * 256 + threadIdx.x) >> 6;
    const int lane = threadIdx.x & 63;
    const float4 hv = *(const float4*)&h1[(size_t)node * HD + lane * 4];
    const float4 sv = *(const float4*)&a_src[lane * 4];
    const float4 dv = *(const float4*)&a_dst[lane * 4];
    float ps = hv.x * sv.x + hv.y * sv.y + hv.z * sv.z + hv.w * sv.w;
    float pd = hv.x * dv.x + hv.y * dv.y + hv.z * dv.z + hv.w * dv.w;
    #pragma unroll
    for (int off = 1; off < 16; off <<= 1) {
        ps += __shfl_xor(ps, off);
        pd += __shfl_xor(pd, off);
    }
    if ((lane & 15) == 0) {
        al_s[node * HEADS + (lane >> 4)] = ps;
        al_d[node * HEADS + (lane >> 4)] = pd;
    }
}

// ---------------- CSR build --------------------------------------------------
__global__ void deg_kernel(const int* __restrict__ ei, int E, int* __restrict__ deg) {
    const int e = blockIdx.x * 256 + threadIdx.x;
    if (e < E) atomicAdd(&deg[ei[E + e]], 1);
}

__global__ __launch_bounds__(1024) void scan_kernel(const int* __restrict__ deg,
                                                    int* __restrict__ offsets) {
    __shared__ int sums[1024];
    const int t = threadIdx.x;
    const int CH = (NNODES + 1023) / 1024;  // 49
    const int lo = t * CH;
    const int hi = min(lo + CH, NNODES);
    int s = 0;
    for (int i = lo; i < hi; ++i) s += deg[i];
    sums[t] = s;
    __syncthreads();
    for (int off = 1; off < 1024; off <<= 1) {
        int v = 0;
        if (t >= off) v = sums[t - off];
        __syncthreads();
        if (t >= off) sums[t] += v;
        __syncthreads();
    }
    int run = (t > 0) ? sums[t - 1] : 0;  // exclusive base
    for (int i = lo; i < hi; ++i) {
        offsets[i] = run;
        run += deg[i];
    }
    if (t == 1023) offsets[NNODES] = sums[1023];
}

__global__ void scatter_kernel(const int* __restrict__ ei, int E,
                               const int* __restrict__ offsets,
                               int* __restrict__ cursor,
                               int* __restrict__ csr_src) {
    const int e = blockIdx.x * 256 + threadIdx.x;
    if (e < E) {
        const int dst = ei[E + e];
        const int src = ei[e];
        const int pos = offsets[dst] + atomicAdd(&cursor[dst], 1);
        csr_src[pos] = src;
    }
}

// ---------------- layer-1 aggregation: online segment-softmax + ELU ----------
__global__ __launch_bounds__(256) void agg1_kernel(const float* __restrict__ h1,
                                                   const float* __restrict__ al_s,
                                                   const float* __restrict__ al_d,
                                                   const int* __restrict__ offsets,
                                                   const int* __restrict__ csr_src,
                                                   const float* __restrict__ b1,
                                                   float* __restrict__ h_act) {
    const int node = (blockIdx.x * 256 + threadIdx.x) >> 6;
    const int lane = threadIdx.x & 63;
    const int h = lane >> 4;  // head for this lane's 4 features
    const float ad = al_d[node * HEADS + h];
    const int start = offsets[node];
    const int end = offsets[node + 1];
    float m = -1e30f, s = 0.f;
    float4 acc = make_float4(0.f, 0.f, 0.f, 0.f);
    for (int i = start; i < end; ++i) {
        const int src = csr_src[i];
        float sc = al_s[src * HEADS + h] + ad;
        sc = sc > 0.f ? sc : NEG_SLOPE * sc;
        const float nm = fmaxf(m, sc);
        const float scale = __expf(m - nm);
        const float p = __expf(sc - nm);
        m = nm;
        s = s * scale + p;
        const float4 v = *(const float4*)&h1[(size_t)src * HD + lane * 4];
        acc.x = acc.x * scale + p * v.x;
        acc.y = acc.y * scale + p * v.y;
        acc.z = acc.z * scale + p * v.z;
        acc.w = acc.w * scale + p * v.w;
    }
    const float inv = 1.f / (s + 1e-16f);
    const float4 bb = *(const float4*)&b1[lane * 4];
    float4 o;
    o.x = acc.x * inv + bb.x;
    o.y = acc.y * inv + bb.y;
    o.z = acc.z * inv + bb.z;
    o.w = acc.w * inv + bb.w;
    // ELU
    o.x = o.x > 0.f ? o.x : expm1f(o.x);
    o.y = o.y > 0.f ? o.y : expm1f(o.y);
    o.z = o.z > 0.f ? o.z : expm1f(o.z);
    o.w = o.w > 0.f ? o.w : expm1f(o.w);
    *(float4*)&h_act[(size_t)node * HD + lane * 4] = o;
}

// ---------------- GEMM2 (+ fused layer-2 score dots) -------------------------
__global__ __launch_bounds__(256) void gemm2_kernel(const float* __restrict__ h_act,
                                                    const float* __restrict__ W2,
                                                    const float* __restrict__ a_s2,
                                                    const float* __restrict__ a_d2,
                                                    float* __restrict__ h2,
                                                    float* __restrict__ al_s,
                                                    float* __restrict__ al_d) {
    __shared__ float w2s[HD * NCLS];   // 40 KB
    __shared__ float rows[4][HD];      // 4 KB
    const int tid = threadIdx.x;
    const int w = tid >> 6;
    const int lane = tid & 63;
    const int node = blockIdx.x * 4 + w;
    // stage W2
    for (int idx = tid * 4; idx < HD * NCLS; idx += 1024)
        *(float4*)&w2s[idx] = *(const float4*)&W2[idx];
    // stage 4 rows of h_act
    *(float4*)&rows[w][lane * 4] = *(const float4*)&h_act[(size_t)node * HD + lane * 4];
    __syncthreads();

    const int c = lane < NCLS ? lane : NCLS - 1;
    float accv = 0.f;
    #pragma unroll 8
    for (int k = 0; k < HD; ++k)
        accv = fmaf(rows[w][k], w2s[k * NCLS + c], accv);

    // fused per-node score dots (1 head, D=40)
    float cs = (lane < NCLS) ? accv * a_s2[c] : 0.f;
    float cd = (lane < NCLS) ? accv * a_d2[c] : 0.f;
    #pragma unroll
    for (int off = 1; off < 64; off <<= 1) {
        cs += __shfl_xor(cs, off);
        cd += __shfl_xor(cd, off);
    }
    if (lane == 0) {
        al_s[node] = cs;
        al_d[node] = cd;
    }
    if (lane < NCLS) h2[(size_t)node * NCLS + lane] = accv;
}

// ---------------- layer-2 aggregation + bias + log_softmax -------------------
__global__ __launch_bounds__(256) void agg2_kernel(const float* __restrict__ h2,
                                                   const float* __restrict__ al_s,
                                                   const float* __restrict__ al_d,
                                                   const int* __restrict__ offsets,
                                                   const int* __restrict__ csr_src,
                                                   const float* __restrict__ b2,
                                                   float* __restrict__ out) {
    const int node = (blockIdx.x * 256 + threadIdx.x) >> 6;
    const int lane = threadIdx.x & 63;
    const int c = lane < NCLS ? lane : NCLS - 1;
    const float ad = al_d[node];
    const int start = offsets[node];
    const int end = offsets[node + 1];
    float m = -1e30f, s = 0.f, acc = 0.f;
    for (int i = start; i < end; ++i) {
        const int src = csr_src[i];
        float sc = al_s[src] + ad;
        sc = sc > 0.f ? sc : NEG_SLOPE * sc;
        const float nm = fmaxf(m, sc);
        const float scale = __expf(m - nm);
        const float p = __expf(sc - nm);
        m = nm;
        s = s * scale + p;
        const float v = h2[(size_t)src * NCLS + c];
        acc = acc * scale + p * v;
    }
    float o = acc / (s + 1e-16f) + b2[c];
    // log_softmax over 40 classes (wave-wide reduce, lanes >= 40 are identity)
    float mx = (lane < NCLS) ? o : -1e30f;
    #pragma unroll
    for (int off = 1; off < 64; off <<= 1) mx = fmaxf(mx, __shfl_xor(mx, off));
    float ex = (lane < NCLS) ? __expf(o - mx) : 0.f;
    #pragma unroll
    for (int off = 1; off < 64; off <<= 1) ex += __shfl_xor(ex, off);
    const float res = o - mx - logf(ex);
    if (lane < NCLS) out[(size_t)node * NCLS + lane] = res;
}

// ---------------- launch -----------------------------------------------------
extern "C" void kernel_launch(void* const* d_in, const int* in_sizes, int n_in,
                              void* d_out, int out_size, void* d_ws, size_t ws_size,
                              hipStream_t stream) {
    const float* x      = (const float*)d_in[0];
    const int*   ei     = (const int*)d_in[1];
    const float* W1     = (const float*)d_in[2];
    const float* a_src1 = (const float*)d_in[3];
    const float* a_dst1 = (const float*)d_in[4];
    const float* b1     = (const float*)d_in[5];
    const float* W2     = (const float*)d_in[6];
    const float* a_src2 = (const float*)d_in[7];
    const float* a_dst2 = (const float*)d_in[8];
    const float* b2     = (const float*)d_in[9];
    float* out = (float*)d_out;
    const int E = in_sizes[1] / 2;

    char* ws = (char*)d_ws;
    size_t off = 0;
    auto alloc = [&](size_t bytes) -> char* {
        char* p = ws + off;
        off += (bytes + 255) & ~(size_t)255;
        return p;
    };
    float* h1     = (float*)alloc((size_t)NNODES * HD * 4);
    float* h_act  = (float*)alloc((size_t)NNODES * HD * 4);
    float* h2     = (float*)alloc((size_t)NNODES * NCLS * 4);
    float* al_s1  = (float*)alloc((size_t)NNODES * HEADS * 4);
    float* al_d1  = (float*)alloc((size_t)NNODES * HEADS * 4);
    float* al_s2  = (float*)alloc((size_t)NNODES * 4);
    float* al_d2  = (float*)alloc((size_t)NNODES * 4);
    int*   deg    = (int*)alloc((size_t)NNODES * 4);
    int*   offs   = (int*)alloc((size_t)(NNODES + 1) * 4);
    int*   cursor = (int*)alloc((size_t)NNODES * 4);
    int*   csrsrc = (int*)alloc((size_t)E * 4);

    hipMemsetAsync(deg, 0, (size_t)NNODES * 4, stream);
    hipMemsetAsync(cursor, 0, (size_t)NNODES * 4, stream);

    const int eb = (E + 255) / 256;
    deg_kernel<<<eb, 256, 0, stream>>>(ei, E, deg);
    scan_kernel<<<1, 1024, 0, stream>>>(deg, offs);
    scatter_kernel<<<eb, 256, 0, stream>>>(ei, E, offs, cursor, csrsrc);

    gemm1_kernel<<<dim3((NNODES + TM - 1) / TM, HD / TN), 256, 0, stream>>>(x, W1, h1);
    al1_kernel<<<NNODES / 4, 256, 0, stream>>>(h1, a_src1, a_dst1, al_s1, al_d1);
    agg1_kernel<<<NNODES / 4, 256, 0, stream>>>(h1, al_s1, al_d1, offs, csrsrc, b1, h_act);
    gemm2_kernel<<<NNODES / 4, 256, 0, stream>>>(h_act, W2, a_src2, a_dst2, h2, al_s2, al_d2);
    agg2_kernel<<<NNODES / 4, 256, 0, stream>>>(h2, al_s2, al_d2, offs, csrsrc, b2, out);
}

// Round 3
// 666.535 us; speedup vs baseline: 1.2082x; 1.2082x over previous
//
#include <hip/hip_runtime.h>
#include <math.h>

#define NNODES 50000
#define FIN 512
#define HID 64
#define HEADS 4
#define HD (HEADS * HID)   // 256
#define NCLS 40
#define NEG_SLOPE 0.2f

typedef __attribute__((ext_vector_type(8))) short short8;
typedef __attribute__((ext_vector_type(4))) float f32x4;

static __device__ inline unsigned short f2bf(float f) {
    unsigned int u = __builtin_bit_cast(unsigned int, f);
    unsigned int r = (u + 0x7FFFu + ((u >> 16) & 1u)) >> 16;
    return (unsigned short)r;
}
static __device__ inline float bf2f(unsigned short b) {
    return __builtin_bit_cast(float, (unsigned int)b << 16);
}

// ---------------- W1 cast+transpose: W1[512,256] fp32 -> W1t[256,512] bf16 ---
__global__ __launch_bounds__(256) void w1t_kernel(const float* __restrict__ W1,
                                                  unsigned short* __restrict__ W1t) {
    const int idx = blockIdx.x * 256 + threadIdx.x;
    const int k = idx >> 8;          // 0..511
    const int n = idx & 255;         // 0..255
    W1t[n * FIN + k] = f2bf(W1[idx]);
}

// ---------------- GEMM1: h1[N,256](bf16) = x[N,512] @ W1[512,256] via MFMA ---
#define BM 128
#define BN 128
#define BK 32
#define ASTRIDE 40   // padded bf16 row stride

__global__ __launch_bounds__(256) void gemm1_kernel(const float* __restrict__ x,
                                                    const unsigned short* __restrict__ W1t,
                                                    unsigned short* __restrict__ h1) {
    __shared__ unsigned short As[BM][ASTRIDE];  // [m][k] bf16
    __shared__ unsigned short Bs[BN][ASTRIDE];  // [n][k] bf16
    const int m0 = blockIdx.x * BM;
    const int n0 = blockIdx.y * BN;
    const int tid = threadIdx.x;
    const int wave = tid >> 6;
    const int lane = tid & 63;
    const int wm = wave >> 1;        // 0..1
    const int wn = wave & 1;         // 0..1
    const int quad = lane >> 4;
    const int col = lane & 15;

    f32x4 acc[4][4] = {};

    for (int k0 = 0; k0 < FIN; k0 += BK) {
        // ---- stage A: 128 rows x 32 k fp32 -> bf16 (4 elems/thread/iter) ----
        #pragma unroll
        for (int it = 0; it < 4; ++it) {
            const int row = it * 32 + (tid >> 3);
            const int kk = (tid & 7) * 4;
            const int gm = m0 + row;
            float4 v = make_float4(0.f, 0.f, 0.f, 0.f);
            if (gm < NNODES)
                v = *(const float4*)&x[(size_t)gm * FIN + k0 + kk];
            ushort4 p;
            p.x = f2bf(v.x); p.y = f2bf(v.y); p.z = f2bf(v.z); p.w = f2bf(v.w);
            *(ushort4*)&As[row][kk] = p;
        }
        // ---- stage B: 128 n-rows x 32 k bf16. uint4 = 8 bf16, need TWO per
        //      16-element half-row (R2 bug: only one was written -> NaN) ------
        {
            const int row = tid >> 1;
            const int kh = (tid & 1) * 16;
            const size_t gb = (size_t)(n0 + row) * FIN + k0 + kh;
            const uint4 raw0 = *(const uint4*)&W1t[gb];
            const uint4 raw1 = *(const uint4*)&W1t[gb + 8];
            *(uint4*)&Bs[row][kh]     = raw0;
            *(uint4*)&Bs[row][kh + 8] = raw1;
        }
        __syncthreads();

        short8 af[4], bf[4];
        #pragma unroll
        for (int i = 0; i < 4; ++i)
            af[i] = *(const short8*)&As[wm * 64 + i * 16 + col][quad * 8];
        #pragma unroll
        for (int j = 0; j < 4; ++j)
            bf[j] = *(const short8*)&Bs[wn * 64 + j * 16 + col][quad * 8];
        #pragma unroll
        for (int i = 0; i < 4; ++i)
            #pragma unroll
            for (int j = 0; j < 4; ++j)
                acc[i][j] = __builtin_amdgcn_mfma_f32_16x16x32_bf16(af[i], bf[j], acc[i][j], 0, 0, 0);
        __syncthreads();
    }

    // epilogue: D row = quad*4 + reg, col = lane&15 (m89-verified layout)
    #pragma unroll
    for (int i = 0; i < 4; ++i) {
        #pragma unroll
        for (int reg = 0; reg < 4; ++reg) {
            const int gm = m0 + wm * 64 + i * 16 + quad * 4 + reg;
            if (gm < NNODES) {
                #pragma unroll
                for (int j = 0; j < 4; ++j) {
                    const int gc = n0 + wn * 64 + j * 16 + col;
                    h1[(size_t)gm * HD + gc] = f2bf(acc[i][j][reg]);
                }
            }
        }
    }
}

// ---------------- per-node attention scores for layer 1 ----------------------
__global__ __launch_bounds__(256) void al1_kernel(const unsigned short* __restrict__ h1,
                                                  const float* __restrict__ a_src,
                                                  const float* __restrict__ a_dst,
                                                  float* __restrict__ al_s,
                                                  float* __restrict__ al_d) {
    const int node = (blockIdx.x * 256 + threadIdx.x) >> 6;
    const int lane = threadIdx.x & 63;
    const ushort4 hb = *(const ushort4*)&h1[(size_t)node * HD + lane * 4];
    const float4 sv = *(const float4*)&a_src[lane * 4];
    const float4 dv = *(const float4*)&a_dst[lane * 4];
    const float h0 = bf2f(hb.x), h1v = bf2f(hb.y), h2v = bf2f(hb.z), h3 = bf2f(hb.w);
    float ps = h0 * sv.x + h1v * sv.y + h2v * sv.z + h3 * sv.w;
    float pd = h0 * dv.x + h1v * dv.y + h2v * dv.z + h3 * dv.w;
    #pragma unroll
    for (int off = 1; off < 16; off <<= 1) {
        ps += __shfl_xor(ps, off);
        pd += __shfl_xor(pd, off);
    }
    if ((lane & 15) == 0) {
        al_s[node * HEADS + (lane >> 4)] = ps;
        al_d[node * HEADS + (lane >> 4)] = pd;
    }
}

// ---------------- CSR build --------------------------------------------------
__global__ void deg_kernel(const int* __restrict__ ei, int E, int* __restrict__ deg) {
    const int e = blockIdx.x * 256 + threadIdx.x;
    if (e < E) atomicAdd(&deg[ei[E + e]], 1);
}

__global__ __launch_bounds__(1024) void scan_kernel(const int* __restrict__ deg,
                                                    int* __restrict__ offsets) {
    __shared__ int sums[1024];
    const int t = threadIdx.x;
    const int CH = (NNODES + 1023) / 1024;  // 49
    const int lo = t * CH;
    const int hi = min(lo + CH, NNODES);
    int s = 0;
    for (int i = lo; i < hi; ++i) s += deg[i];
    sums[t] = s;
    __syncthreads();
    for (int off = 1; off < 1024; off <<= 1) {
        int v = 0;
        if (t >= off) v = sums[t - off];
        __syncthreads();
        if (t >= off) sums[t] += v;
        __syncthreads();
    }
    int run = (t > 0) ? sums[t - 1] : 0;
    for (int i = lo; i < hi; ++i) {
        offsets[i] = run;
        run += deg[i];
    }
    if (t == 1023) offsets[NNODES] = sums[1023];
}

__global__ void scatter_kernel(const int* __restrict__ ei, int E,
                               const int* __restrict__ offsets,
                               int* __restrict__ cursor,
                               int* __restrict__ csr_src) {
    const int e = blockIdx.x * 256 + threadIdx.x;
    if (e < E) {
        const int dst = ei[E + e];
        const int src = ei[e];
        const int pos = offsets[dst] + atomicAdd(&cursor[dst], 1);
        csr_src[pos] = src;
    }
}

// ---------------- layer-1 aggregation: online segment-softmax + ELU ----------
__global__ __launch_bounds__(256) void agg1_kernel(const unsigned short* __restrict__ h1,
                                                   const float* __restrict__ al_s,
                                                   const float* __restrict__ al_d,
                                                   const int* __restrict__ offsets,
                                                   const int* __restrict__ csr_src,
                                                   const float* __restrict__ b1,
                                                   unsigned short* __restrict__ h_act) {
    const int node = (blockIdx.x * 256 + threadIdx.x) >> 6;
    const int lane = threadIdx.x & 63;
    const int h = lane >> 4;
    const float ad = al_d[node * HEADS + h];
    const int start = offsets[node];
    const int end = offsets[node + 1];
    float m = -1e30f, s = 0.f;
    float4 acc = make_float4(0.f, 0.f, 0.f, 0.f);
    for (int i = start; i < end; ++i) {
        const int src = csr_src[i];
        float sc = al_s[src * HEADS + h] + ad;
        sc = sc > 0.f ? sc : NEG_SLOPE * sc;
        const float nm = fmaxf(m, sc);
        const float scale = __expf(m - nm);
        const float p = __expf(sc - nm);
        m = nm;
        s = s * scale + p;
        const ushort4 vb = *(const ushort4*)&h1[(size_t)src * HD + lane * 4];
        acc.x = acc.x * scale + p * bf2f(vb.x);
        acc.y = acc.y * scale + p * bf2f(vb.y);
        acc.z = acc.z * scale + p * bf2f(vb.z);
        acc.w = acc.w * scale + p * bf2f(vb.w);
    }
    const float inv = 1.f / (s + 1e-16f);
    const float4 bb = *(const float4*)&b1[lane * 4];
    float4 o;
    o.x = acc.x * inv + bb.x;
    o.y = acc.y * inv + bb.y;
    o.z = acc.z * inv + bb.z;
    o.w = acc.w * inv + bb.w;
    o.x = o.x > 0.f ? o.x : expm1f(o.x);
    o.y = o.y > 0.f ? o.y : expm1f(o.y);
    o.z = o.z > 0.f ? o.z : expm1f(o.z);
    o.w = o.w > 0.f ? o.w : expm1f(o.w);
    ushort4 ob;
    ob.x = f2bf(o.x); ob.y = f2bf(o.y); ob.z = f2bf(o.z); ob.w = f2bf(o.w);
    *(ushort4*)&h_act[(size_t)node * HD + lane * 4] = ob;
}

// ---------------- GEMM2 (+ fused layer-2 score dots), 16 nodes/block ---------
#define G2N 16
__global__ __launch_bounds__(256) void gemm2_kernel(const unsigned short* __restrict__ h_act,
                                                    const float* __restrict__ W2,
                                                    const float* __restrict__ a_s2,
                                                    const float* __restrict__ a_d2,
                                                    unsigned short* __restrict__ h2,
                                                    float* __restrict__ al_s,
                                                    float* __restrict__ al_d) {
    __shared__ float w2s[HD * NCLS];   // 40 KB
    __shared__ float rows[G2N][HD];    // 16 KB
    const int tid = threadIdx.x;
    const int w = tid >> 6;
    const int lane = tid & 63;
    const int base = blockIdx.x * G2N;
    for (int idx = tid * 4; idx < HD * NCLS; idx += 1024)
        *(float4*)&w2s[idx] = *(const float4*)&W2[idx];
    #pragma unroll
    for (int it = 0; it < 2; ++it) {
        const int idx = it * 2048 + tid * 8;
        const uint4 raw = *(const uint4*)&h_act[(size_t)base * HD + idx];
        float* rp = &rows[0][0] + idx;
        rp[0] = bf2f((unsigned short)(raw.x & 0xFFFF));
        rp[1] = bf2f((unsigned short)(raw.x >> 16));
        rp[2] = bf2f((unsigned short)(raw.y & 0xFFFF));
        rp[3] = bf2f((unsigned short)(raw.y >> 16));
        rp[4] = bf2f((unsigned short)(raw.z & 0xFFFF));
        rp[5] = bf2f((unsigned short)(raw.z >> 16));
        rp[6] = bf2f((unsigned short)(raw.w & 0xFFFF));
        rp[7] = bf2f((unsigned short)(raw.w >> 16));
    }
    __syncthreads();

    const int c = lane < NCLS ? lane : NCLS - 1;
    const float as_c = a_s2[c];
    const float ad_c = a_d2[c];
    #pragma unroll
    for (int r = 0; r < 4; ++r) {
        const int nl = w * 4 + r;
        const int node = base + nl;
        float accv = 0.f;
        #pragma unroll 8
        for (int k = 0; k < HD; ++k)
            accv = fmaf(rows[nl][k], w2s[k * NCLS + c], accv);
        float cs = (lane < NCLS) ? accv * as_c : 0.f;
        float cd = (lane < NCLS) ? accv * ad_c : 0.f;
        #pragma unroll
        for (int off = 1; off < 64; off <<= 1) {
            cs += __shfl_xor(cs, off);
            cd += __shfl_xor(cd, off);
        }
        if (lane == 0) {
            al_s[node] = cs;
            al_d[node] = cd;
        }
        if (lane < NCLS) h2[(size_t)node * NCLS + lane] = f2bf(accv);
    }
}

// ---------------- layer-2 aggregation + bias + log_softmax -------------------
__global__ __launch_bounds__(256) void agg2_kernel(const unsigned short* __restrict__ h2,
                                                   const float* __restrict__ al_s,
                                                   const float* __restrict__ al_d,
                                                   const int* __restrict__ offsets,
                                                   const int* __restrict__ csr_src,
                                                   const float* __restrict__ b2,
                                                   float* __restrict__ out) {
    const int node = (blockIdx.x * 256 + threadIdx.x) >> 6;
    const int lane = threadIdx.x & 63;
    const int c = lane < NCLS ? lane : NCLS - 1;
    const float ad = al_d[node];
    const int start = offsets[node];
    const int end = offsets[node + 1];
    float m = -1e30f, s = 0.f, acc = 0.f;
    for (int i = start; i < end; ++i) {
        const int src = csr_src[i];
        float sc = al_s[src] + ad;
        sc = sc > 0.f ? sc : NEG_SLOPE * sc;
        const float nm = fmaxf(m, sc);
        const float scale = __expf(m - nm);
        const float p = __expf(sc - nm);
        m = nm;
        s = s * scale + p;
        const float v = bf2f(h2[(size_t)src * NCLS + c]);
        acc = acc * scale + p * v;
    }
    float o = acc / (s + 1e-16f) + b2[c];
    float mx = (lane < NCLS) ? o : -1e30f;
    #pragma unroll
    for (int off = 1; off < 64; off <<= 1) mx = fmaxf(mx, __shfl_xor(mx, off));
    float ex = (lane < NCLS) ? __expf(o - mx) : 0.f;
    #pragma unroll
    for (int off = 1; off < 64; off <<= 1) ex += __shfl_xor(ex, off);
    const float res = o - mx - logf(ex);
    if (lane < NCLS) out[(size_t)node * NCLS + lane] = res;
}

// ---------------- launch -----------------------------------------------------
extern "C" void kernel_launch(void* const* d_in, const int* in_sizes, int n_in,
                              void* d_out, int out_size, void* d_ws, size_t ws_size,
                              hipStream_t stream) {
    const float* x      = (const float*)d_in[0];
    const int*   ei     = (const int*)d_in[1];
    const float* W1     = (const float*)d_in[2];
    const float* a_src1 = (const float*)d_in[3];
    const float* a_dst1 = (const float*)d_in[4];
    const float* b1     = (const float*)d_in[5];
    const float* W2     = (const float*)d_in[6];
    const float* a_src2 = (const float*)d_in[7];
    const float* a_dst2 = (const float*)d_in[8];
    const float* b2     = (const float*)d_in[9];
    float* out = (float*)d_out;
    const int E = in_sizes[1] / 2;

    char* ws = (char*)d_ws;
    size_t off = 0;
    auto alloc = [&](size_t bytes) -> char* {
        char* p = ws + off;
        off += (bytes + 255) & ~(size_t)255;
        return p;
    };
    unsigned short* W1t   = (unsigned short*)alloc((size_t)FIN * HD * 2);
    unsigned short* h1    = (unsigned short*)alloc((size_t)NNODES * HD * 2);
    unsigned short* h_act = (unsigned short*)alloc((size_t)NNODES * HD * 2);
    unsigned short* h2    = (unsigned short*)alloc((size_t)NNODES * NCLS * 2);
    float* al_s1  = (float*)alloc((size_t)NNODES * HEADS * 4);
    float* al_d1  = (float*)alloc((size_t)NNODES * HEADS * 4);
    float* al_s2  = (float*)alloc((size_t)NNODES * 4);
    float* al_d2  = (float*)alloc((size_t)NNODES * 4);
    int*   deg    = (int*)alloc((size_t)NNODES * 4);
    int*   offs   = (int*)alloc((size_t)(NNODES + 1) * 4);
    int*   cursor = (int*)alloc((size_t)NNODES * 4);
    int*   csrsrc = (int*)alloc((size_t)E * 4);

    hipMemsetAsync(deg, 0, (size_t)NNODES * 4, stream);
    hipMemsetAsync(cursor, 0, (size_t)NNODES * 4, stream);

    const int eb = (E + 255) / 256;
    w1t_kernel<<<FIN * HD / 256, 256, 0, stream>>>(W1, W1t);
    deg_kernel<<<eb, 256, 0, stream>>>(ei, E, deg);
    scan_kernel<<<1, 1024, 0, stream>>>(deg, offs);
    scatter_kernel<<<eb, 256, 0, stream>>>(ei, E, offs, cursor, csrsrc);

    gemm1_kernel<<<dim3((NNODES + BM - 1) / BM, HD / BN), 256, 0, stream>>>(x, W1t, h1);
    al1_kernel<<<NNODES / 4, 256, 0, stream>>>(h1, a_src1, a_dst1, al_s1, al_d1);
    agg1_kernel<<<NNODES / 4, 256, 0, stream>>>(h1, al_s1, al_d1, offs, csrsrc, b1, h_act);
    gemm2_kernel<<<NNODES / G2N, 256, 0, stream>>>(h_act, W2, a_src2, a_dst2, h2, al_s2, al_d2);
    agg2_kernel<<<NNODES / 4, 256, 0, stream>>>(h2, al_s2, al_d2, offs, csrsrc, b2, out);
}

// Round 4
// 642.148 us; speedup vs baseline: 1.2541x; 1.0380x over previous
//
#include <hip/hip_runtime.h>
#include <math.h>

#define NNODES 50000
#define FIN 512
#define HID 64
#define HEADS 4
#define HD (HEADS * HID)   // 256
#define NCLS 40
#define NEG_SLOPE 0.2f

typedef __attribute__((ext_vector_type(8))) short short8;
typedef __attribute__((ext_vector_type(4))) float f32x4;

static __device__ inline unsigned short f2bf(float f) {
    unsigned int u = __builtin_bit_cast(unsigned int, f);
    unsigned int r = (u + 0x7FFFu + ((u >> 16) & 1u)) >> 16;
    return (unsigned short)r;
}
static __device__ inline float bf2f(unsigned short b) {
    return __builtin_bit_cast(float, (unsigned int)b << 16);
}

// ---------------- W1 cast+transpose: W1[512,256] fp32 -> W1t[256,512] bf16 ---
__global__ __launch_bounds__(256) void w1t_kernel(const float* __restrict__ W1,
                                                  unsigned short* __restrict__ W1t) {
    const int idx = blockIdx.x * 256 + threadIdx.x;
    const int k = idx >> 8;          // 0..511
    const int n = idx & 255;         // 0..255
    W1t[n * FIN + k] = f2bf(W1[idx]);
}

// ---------------- GEMM1: h1[N,256](bf16) = x[N,512] @ W1[512,256] via MFMA ---
#define BM 128
#define BN 128
#define BK 32
#define ASTRIDE 40   // padded bf16 row stride

__global__ __launch_bounds__(256) void gemm1_kernel(const float* __restrict__ x,
                                                    const unsigned short* __restrict__ W1t,
                                                    unsigned short* __restrict__ h1) {
    __shared__ unsigned short As[BM][ASTRIDE];  // [m][k] bf16
    __shared__ unsigned short Bs[BN][ASTRIDE];  // [n][k] bf16
    const int m0 = blockIdx.x * BM;
    const int n0 = blockIdx.y * BN;
    const int tid = threadIdx.x;
    const int wave = tid >> 6;
    const int lane = tid & 63;
    const int wm = wave >> 1;        // 0..1
    const int wn = wave & 1;         // 0..1
    const int quad = lane >> 4;
    const int col = lane & 15;

    f32x4 acc[4][4] = {};

    for (int k0 = 0; k0 < FIN; k0 += BK) {
        #pragma unroll
        for (int it = 0; it < 4; ++it) {
            const int row = it * 32 + (tid >> 3);
            const int kk = (tid & 7) * 4;
            const int gm = m0 + row;
            float4 v = make_float4(0.f, 0.f, 0.f, 0.f);
            if (gm < NNODES)
                v = *(const float4*)&x[(size_t)gm * FIN + k0 + kk];
            ushort4 p;
            p.x = f2bf(v.x); p.y = f2bf(v.y); p.z = f2bf(v.z); p.w = f2bf(v.w);
            *(ushort4*)&As[row][kk] = p;
        }
        {
            const int row = tid >> 1;
            const int kh = (tid & 1) * 16;
            const size_t gb = (size_t)(n0 + row) * FIN + k0 + kh;
            const uint4 raw0 = *(const uint4*)&W1t[gb];
            const uint4 raw1 = *(const uint4*)&W1t[gb + 8];
            *(uint4*)&Bs[row][kh]     = raw0;
            *(uint4*)&Bs[row][kh + 8] = raw1;
        }
        __syncthreads();

        short8 af[4], bf[4];
        #pragma unroll
        for (int i = 0; i < 4; ++i)
            af[i] = *(const short8*)&As[wm * 64 + i * 16 + col][quad * 8];
        #pragma unroll
        for (int j = 0; j < 4; ++j)
            bf[j] = *(const short8*)&Bs[wn * 64 + j * 16 + col][quad * 8];
        #pragma unroll
        for (int i = 0; i < 4; ++i)
            #pragma unroll
            for (int j = 0; j < 4; ++j)
                acc[i][j] = __builtin_amdgcn_mfma_f32_16x16x32_bf16(af[i], bf[j], acc[i][j], 0, 0, 0);
        __syncthreads();
    }

    #pragma unroll
    for (int i = 0; i < 4; ++i) {
        #pragma unroll
        for (int reg = 0; reg < 4; ++reg) {
            const int gm = m0 + wm * 64 + i * 16 + quad * 4 + reg;
            if (gm < NNODES) {
                #pragma unroll
                for (int j = 0; j < 4; ++j) {
                    const int gc = n0 + wn * 64 + j * 16 + col;
                    h1[(size_t)gm * HD + gc] = f2bf(acc[i][j][reg]);
                }
            }
        }
    }
}

// ---------------- per-node attention scores for layer 1 ----------------------
__global__ __launch_bounds__(256) void al1_kernel(const unsigned short* __restrict__ h1,
                                                  const float* __restrict__ a_src,
                                                  const float* __restrict__ a_dst,
                                                  float* __restrict__ al_s,
                                                  float* __restrict__ al_d) {
    const int node = (blockIdx.x * 256 + threadIdx.x) >> 6;
    const int lane = threadIdx.x & 63;
    const ushort4 hb = *(const ushort4*)&h1[(size_t)node * HD + lane * 4];
    const float4 sv = *(const float4*)&a_src[lane * 4];
    const float4 dv = *(const float4*)&a_dst[lane * 4];
    const float h0 = bf2f(hb.x), h1v = bf2f(hb.y), h2v = bf2f(hb.z), h3 = bf2f(hb.w);
    float ps = h0 * sv.x + h1v * sv.y + h2v * sv.z + h3 * sv.w;
    float pd = h0 * dv.x + h1v * dv.y + h2v * dv.z + h3 * dv.w;
    #pragma unroll
    for (int off = 1; off < 16; off <<= 1) {
        ps += __shfl_xor(ps, off);
        pd += __shfl_xor(pd, off);
    }
    if ((lane & 15) == 0) {
        al_s[node * HEADS + (lane >> 4)] = ps;
        al_d[node * HEADS + (lane >> 4)] = pd;
    }
}

// ---------------- CSR build --------------------------------------------------
__global__ void deg_kernel(const int* __restrict__ ei, int E, int* __restrict__ deg) {
    const int e = blockIdx.x * 256 + threadIdx.x;
    if (e < E) atomicAdd(&deg[ei[E + e]], 1);
}

__global__ __launch_bounds__(1024) void scan_kernel(const int* __restrict__ deg,
                                                    int* __restrict__ offsets) {
    __shared__ int sums[1024];
    const int t = threadIdx.x;
    const int CH = (NNODES + 1023) / 1024;  // 49
    const int lo = t * CH;
    const int hi = min(lo + CH, NNODES);
    int s = 0;
    for (int i = lo; i < hi; ++i) s += deg[i];
    sums[t] = s;
    __syncthreads();
    for (int off = 1; off < 1024; off <<= 1) {
        int v = 0;
        if (t >= off) v = sums[t - off];
        __syncthreads();
        if (t >= off) sums[t] += v;
        __syncthreads();
    }
    int run = (t > 0) ? sums[t - 1] : 0;
    for (int i = lo; i < hi; ++i) {
        offsets[i] = run;
        run += deg[i];
    }
    if (t == 1023) offsets[NNODES] = sums[1023];
}

__global__ void scatter_kernel(const int* __restrict__ ei, int E,
                               const int* __restrict__ offsets,
                               int* __restrict__ cursor,
                               int* __restrict__ csr_src) {
    const int e = blockIdx.x * 256 + threadIdx.x;
    if (e < E) {
        const int dst = ei[E + e];
        const int src = ei[e];
        const int pos = offsets[dst] + atomicAdd(&cursor[dst], 1);
        csr_src[pos] = src;
    }
}

// ---------------- layer-1 aggregation: dual-stream pipelined online softmax --
// Padding edges use score=-inf: p=exp(-inf)=0, scale=exp(0)=1 -> exact no-op,
// so the hot loop is branchless and each wave keeps ~4 gathers in flight.
__global__ __launch_bounds__(256) void agg1_kernel(const unsigned short* __restrict__ h1,
                                                   const float* __restrict__ al_s,
                                                   const float* __restrict__ al_d,
                                                   const int* __restrict__ offsets,
                                                   const int* __restrict__ csr_src,
                                                   const float* __restrict__ b1,
                                                   unsigned short* __restrict__ h_act) {
    const int node = (blockIdx.x * 256 + threadIdx.x) >> 6;
    const int lane = threadIdx.x & 63;
    const int h = lane >> 4;
    const float ad = al_d[node * HEADS + h];
    const int start = offsets[node];
    const int end = offsets[node + 1];   // end > start always (self-loops)
    const int last = end - 1;

    float mA = -1e30f, sA = 0.f, mB = -1e30f, sB = 0.f;
    float4 aA = make_float4(0.f, 0.f, 0.f, 0.f);
    float4 aB = make_float4(0.f, 0.f, 0.f, 0.f);

#define ROW1(s_) (*(const ushort4*)&h1[(size_t)(s_) * HD + lane * 4])
#define PROC1(sc_, v_, m_, s_, a_)                        \
    {                                                     \
        float e_ = sc_ + ad;                              \
        e_ = e_ > 0.f ? e_ : NEG_SLOPE * e_;              \
        const float nm_ = fmaxf(m_, e_);                  \
        const float scl_ = __expf(m_ - nm_);              \
        const float p_ = __expf(e_ - nm_);                \
        m_ = nm_;                                         \
        s_ = s_ * scl_ + p_;                              \
        a_.x = a_.x * scl_ + p_ * bf2f(v_.x);             \
        a_.y = a_.y * scl_ + p_ * bf2f(v_.y);             \
        a_.z = a_.z * scl_ + p_ * bf2f(v_.z);             \
        a_.w = a_.w * scl_ + p_ * bf2f(v_.w);             \
    }

    // pipeline prologue: edges start, start+1
    int srcA = csr_src[start];
    int srcB = csr_src[min(start + 1, last)];
    float scA = al_s[srcA * HEADS + h];
    float scB = (start + 1 < end) ? al_s[srcB * HEADS + h] : -__builtin_inff();
    ushort4 vA = ROW1(srcA);
    ushort4 vB = ROW1(srcB);

    for (int i = start; i < end; i += 2) {
        const int j = i + 2;
        const int nsrcA = csr_src[min(j, last)];
        const int nsrcB = csr_src[min(j + 1, last)];
        const float nscA = (j < end) ? al_s[nsrcA * HEADS + h] : -__builtin_inff();
        const float nscB = (j + 1 < end) ? al_s[nsrcB * HEADS + h] : -__builtin_inff();
        const ushort4 nvA = ROW1(nsrcA);
        const ushort4 nvB = ROW1(nsrcB);
        PROC1(scA, vA, mA, sA, aA);
        PROC1(scB, vB, mB, sB, aB);
        scA = nscA; vA = nvA; scB = nscB; vB = nvB;
    }
    // merge stream B into A (mB=-1e30 if no B edges -> eB=0)
    const float M = fmaxf(mA, mB);
    const float eA = __expf(mA - M);
    const float eB = __expf(mB - M);
    const float s = sA * eA + sB * eB;
    float4 acc;
    acc.x = aA.x * eA + aB.x * eB;
    acc.y = aA.y * eA + aB.y * eB;
    acc.z = aA.z * eA + aB.z * eB;
    acc.w = aA.w * eA + aB.w * eB;

    const float inv = 1.f / (s + 1e-16f);
    const float4 bb = *(const float4*)&b1[lane * 4];
    float4 o;
    o.x = acc.x * inv + bb.x;
    o.y = acc.y * inv + bb.y;
    o.z = acc.z * inv + bb.z;
    o.w = acc.w * inv + bb.w;
    o.x = o.x > 0.f ? o.x : expm1f(o.x);
    o.y = o.y > 0.f ? o.y : expm1f(o.y);
    o.z = o.z > 0.f ? o.z : expm1f(o.z);
    o.w = o.w > 0.f ? o.w : expm1f(o.w);
    ushort4 ob;
    ob.x = f2bf(o.x); ob.y = f2bf(o.y); ob.z = f2bf(o.z); ob.w = f2bf(o.w);
    *(ushort4*)&h_act[(size_t)node * HD + lane * 4] = ob;
#undef ROW1
#undef PROC1
}

// ---------------- GEMM2 (+ fused layer-2 score dots), 16 nodes/block ---------
#define G2N 16
__global__ __launch_bounds__(256) void gemm2_kernel(const unsigned short* __restrict__ h_act,
                                                    const float* __restrict__ W2,
                                                    const float* __restrict__ a_s2,
                                                    const float* __restrict__ a_d2,
                                                    unsigned short* __restrict__ h2,
                                                    float* __restrict__ al_s,
                                                    float* __restrict__ al_d) {
    __shared__ float w2s[HD * NCLS];   // 40 KB
    __shared__ float rows[G2N][HD];    // 16 KB
    const int tid = threadIdx.x;
    const int w = tid >> 6;
    const int lane = tid & 63;
    const int base = blockIdx.x * G2N;
    for (int idx = tid * 4; idx < HD * NCLS; idx += 1024)
        *(float4*)&w2s[idx] = *(const float4*)&W2[idx];
    #pragma unroll
    for (int it = 0; it < 2; ++it) {
        const int idx = it * 2048 + tid * 8;
        const uint4 raw = *(const uint4*)&h_act[(size_t)base * HD + idx];
        float* rp = &rows[0][0] + idx;
        rp[0] = bf2f((unsigned short)(raw.x & 0xFFFF));
        rp[1] = bf2f((unsigned short)(raw.x >> 16));
        rp[2] = bf2f((unsigned short)(raw.y & 0xFFFF));
        rp[3] = bf2f((unsigned short)(raw.y >> 16));
        rp[4] = bf2f((unsigned short)(raw.z & 0xFFFF));
        rp[5] = bf2f((unsigned short)(raw.z >> 16));
        rp[6] = bf2f((unsigned short)(raw.w & 0xFFFF));
        rp[7] = bf2f((unsigned short)(raw.w >> 16));
    }
    __syncthreads();

    const int c = lane < NCLS ? lane : NCLS - 1;
    const float as_c = a_s2[c];
    const float ad_c = a_d2[c];
    #pragma unroll
    for (int r = 0; r < 4; ++r) {
        const int nl = w * 4 + r;
        const int node = base + nl;
        float accv = 0.f;
        #pragma unroll 8
        for (int k = 0; k < HD; ++k)
            accv = fmaf(rows[nl][k], w2s[k * NCLS + c], accv);
        float cs = (lane < NCLS) ? accv * as_c : 0.f;
        float cd = (lane < NCLS) ? accv * ad_c : 0.f;
        #pragma unroll
        for (int off = 1; off < 64; off <<= 1) {
            cs += __shfl_xor(cs, off);
            cd += __shfl_xor(cd, off);
        }
        if (lane == 0) {
            al_s[node] = cs;
            al_d[node] = cd;
        }
        if (lane < NCLS) h2[(size_t)node * NCLS + lane] = f2bf(accv);
    }
}

// ---------------- layer-2 aggregation: dual-stream pipelined + log_softmax ---
__global__ __launch_bounds__(256) void agg2_kernel(const unsigned short* __restrict__ h2,
                                                   const float* __restrict__ al_s,
                                                   const float* __restrict__ al_d,
                                                   const int* __restrict__ offsets,
                                                   const int* __restrict__ csr_src,
                                                   const float* __restrict__ b2,
                                                   float* __restrict__ out) {
    const int node = (blockIdx.x * 256 + threadIdx.x) >> 6;
    const int lane = threadIdx.x & 63;
    const int c = lane < NCLS ? lane : NCLS - 1;
    const float ad = al_d[node];
    const int start = offsets[node];
    const int end = offsets[node + 1];
    const int last = end - 1;

    float mA = -1e30f, sA = 0.f, accA = 0.f;
    float mB = -1e30f, sB = 0.f, accB = 0.f;

#define PROC2(sc_, v_, m_, s_, a_)                        \
    {                                                     \
        float e_ = sc_ + ad;                              \
        e_ = e_ > 0.f ? e_ : NEG_SLOPE * e_;              \
        const float nm_ = fmaxf(m_, e_);                  \
        const float scl_ = __expf(m_ - nm_);              \
        const float p_ = __expf(e_ - nm_);                \
        m_ = nm_;                                         \
        s_ = s_ * scl_ + p_;                              \
        a_ = a_ * scl_ + p_ * v_;                         \
    }

    int srcA = csr_src[start];
    int srcB = csr_src[min(start + 1, last)];
    float scA = al_s[srcA];
    float scB = (start + 1 < end) ? al_s[srcB] : -__builtin_inff();
    float vA = bf2f(h2[(size_t)srcA * NCLS + c]);
    float vB = bf2f(h2[(size_t)srcB * NCLS + c]);

    for (int i = start; i < end; i += 2) {
        const int j = i + 2;
        const int nsrcA = csr_src[min(j, last)];
        const int nsrcB = csr_src[min(j + 1, last)];
        const float nscA = (j < end) ? al_s[nsrcA] : -__builtin_inff();
        const float nscB = (j + 1 < end) ? al_s[nsrcB] : -__builtin_inff();
        const float nvA = bf2f(h2[(size_t)nsrcA * NCLS + c]);
        const float nvB = bf2f(h2[(size_t)nsrcB * NCLS + c]);
        PROC2(scA, vA, mA, sA, accA);
        PROC2(scB, vB, mB, sB, accB);
        scA = nscA; vA = nvA; scB = nscB; vB = nvB;
    }
    const float M = fmaxf(mA, mB);
    const float eA = __expf(mA - M);
    const float eB = __expf(mB - M);
    const float s = sA * eA + sB * eB;
    const float acc = accA * eA + accB * eB;
#undef PROC2

    float o = acc / (s + 1e-16f) + b2[c];
    float mx = (lane < NCLS) ? o : -1e30f;
    #pragma unroll
    for (int off = 1; off < 64; off <<= 1) mx = fmaxf(mx, __shfl_xor(mx, off));
    float ex = (lane < NCLS) ? __expf(o - mx) : 0.f;
    #pragma unroll
    for (int off = 1; off < 64; off <<= 1) ex += __shfl_xor(ex, off);
    const float res = o - mx - logf(ex);
    if (lane < NCLS) out[(size_t)node * NCLS + lane] = res;
}

// ---------------- launch -----------------------------------------------------
extern "C" void kernel_launch(void* const* d_in, const int* in_sizes, int n_in,
                              void* d_out, int out_size, void* d_ws, size_t ws_size,
                              hipStream_t stream) {
    const float* x      = (const float*)d_in[0];
    const int*   ei     = (const int*)d_in[1];
    const float* W1     = (const float*)d_in[2];
    const float* a_src1 = (const float*)d_in[3];
    const float* a_dst1 = (const float*)d_in[4];
    const float* b1     = (const float*)d_in[5];
    const float* W2     = (const float*)d_in[6];
    const float* a_src2 = (const float*)d_in[7];
    const float* a_dst2 = (const float*)d_in[8];
    const float* b2     = (const float*)d_in[9];
    float* out = (float*)d_out;
    const int E = in_sizes[1] / 2;

    char* ws = (char*)d_ws;
    size_t off = 0;
    auto alloc = [&](size_t bytes) -> char* {
        char* p = ws + off;
        off += (bytes + 255) & ~(size_t)255;
        return p;
    };
    unsigned short* W1t   = (unsigned short*)alloc((size_t)FIN * HD * 2);
    unsigned short* h1    = (unsigned short*)alloc((size_t)NNODES * HD * 2);
    unsigned short* h_act = (unsigned short*)alloc((size_t)NNODES * HD * 2);
    unsigned short* h2    = (unsigned short*)alloc((size_t)NNODES * NCLS * 2);
    float* al_s1  = (float*)alloc((size_t)NNODES * HEADS * 4);
    float* al_d1  = (float*)alloc((size_t)NNODES * HEADS * 4);
    float* al_s2  = (float*)alloc((size_t)NNODES * 4);
    float* al_d2  = (float*)alloc((size_t)NNODES * 4);
    int*   deg    = (int*)alloc((size_t)NNODES * 4);
    int*   offs   = (int*)alloc((size_t)(NNODES + 1) * 4);
    int*   cursor = (int*)alloc((size_t)NNODES * 4);
    int*   csrsrc = (int*)alloc((size_t)E * 4);

    hipMemsetAsync(deg, 0, (size_t)NNODES * 4, stream);
    hipMemsetAsync(cursor, 0, (size_t)NNODES * 4, stream);

    const int eb = (E + 255) / 256;
    w1t_kernel<<<FIN * HD / 256, 256, 0, stream>>>(W1, W1t);
    deg_kernel<<<eb, 256, 0, stream>>>(ei, E, deg);
    scan_kernel<<<1, 1024, 0, stream>>>(deg, offs);
    scatter_kernel<<<eb, 256, 0, stream>>>(ei, E, offs, cursor, csrsrc);

    gemm1_kernel<<<dim3((NNODES + BM - 1) / BM, HD / BN), 256, 0, stream>>>(x, W1t, h1);
    al1_kernel<<<NNODES / 4, 256, 0, stream>>>(h1, a_src1, a_dst1, al_s1, al_d1);
    agg1_kernel<<<NNODES / 4, 256, 0, stream>>>(h1, al_s1, al_d1, offs, csrsrc, b1, h_act);
    gemm2_kernel<<<NNODES / G2N, 256, 0, stream>>>(h_act, W2, a_src2, a_dst2, h2, al_s2, al_d2);
    agg2_kernel<<<NNODES / 4, 256, 0, stream>>>(h2, al_s2, al_d2, offs, csrsrc, b2, out);
}

// Round 5
// 546.843 us; speedup vs baseline: 1.4726x; 1.1743x over previous
//
#include <hip/hip_runtime.h>
#include <math.h>

#define NNODES 50000
#define FIN 512
#define HID 64
#define HEADS 4
#define HD (HEADS * HID)   // 256
#define NCLS 40
#define NCLSP 48           // padded to 3x16 for MFMA n-tiles
#define NEG_SLOPE 0.2f

typedef __attribute__((ext_vector_type(8))) short short8;
typedef __attribute__((ext_vector_type(4))) float f32x4;

static __device__ inline unsigned short f2bf(float f) {
    unsigned int u = __builtin_bit_cast(unsigned int, f);
    unsigned int r = (u + 0x7FFFu + ((u >> 16) & 1u)) >> 16;
    return (unsigned short)r;
}
static __device__ inline float bf2f(unsigned short b) {
    return __builtin_bit_cast(float, (unsigned int)b << 16);
}

// ---------------- W1 cast+transpose: W1[512,256] fp32 -> W1t[256,512] bf16 ---
__global__ __launch_bounds__(256) void w1t_kernel(const float* __restrict__ W1,
                                                  unsigned short* __restrict__ W1t) {
    const int idx = blockIdx.x * 256 + threadIdx.x;
    const int k = idx >> 8;          // 0..511
    const int n = idx & 255;         // 0..255
    W1t[n * FIN + k] = f2bf(W1[idx]);
}

// ---------------- W2 cast+transpose: W2[256,40] fp32 -> W2t[48][256] bf16 ----
__global__ __launch_bounds__(256) void w2t_kernel(const float* __restrict__ W2,
                                                  unsigned short* __restrict__ W2t) {
    const int idx = blockIdx.x * 256 + threadIdx.x;  // 48 blocks
    const int n = idx >> 8;          // 0..47
    const int k = idx & 255;         // 0..255
    W2t[n * HD + k] = (n < NCLS) ? f2bf(W2[k * NCLS + n]) : (unsigned short)0;
}

// ---------------- GEMM1: h1[N,256](bf16) = x[N,512] @ W1[512,256] via MFMA ---
#define BM 128
#define BN 128
#define BK 32
#define ASTRIDE 40   // padded bf16 row stride

__global__ __launch_bounds__(256) void gemm1_kernel(const float* __restrict__ x,
                                                    const unsigned short* __restrict__ W1t,
                                                    unsigned short* __restrict__ h1) {
    __shared__ unsigned short As[BM][ASTRIDE];  // [m][k] bf16
    __shared__ unsigned short Bs[BN][ASTRIDE];  // [n][k] bf16
    const int m0 = blockIdx.x * BM;
    const int n0 = blockIdx.y * BN;
    const int tid = threadIdx.x;
    const int wave = tid >> 6;
    const int lane = tid & 63;
    const int wm = wave >> 1;        // 0..1
    const int wn = wave & 1;         // 0..1
    const int quad = lane >> 4;
    const int col = lane & 15;

    f32x4 acc[4][4] = {};

    for (int k0 = 0; k0 < FIN; k0 += BK) {
        #pragma unroll
        for (int it = 0; it < 4; ++it) {
            const int row = it * 32 + (tid >> 3);
            const int kk = (tid & 7) * 4;
            const int gm = m0 + row;
            float4 v = make_float4(0.f, 0.f, 0.f, 0.f);
            if (gm < NNODES)
                v = *(const float4*)&x[(size_t)gm * FIN + k0 + kk];
            ushort4 p;
            p.x = f2bf(v.x); p.y = f2bf(v.y); p.z = f2bf(v.z); p.w = f2bf(v.w);
            *(ushort4*)&As[row][kk] = p;
        }
        {
            const int row = tid >> 1;
            const int kh = (tid & 1) * 16;
            const size_t gb = (size_t)(n0 + row) * FIN + k0 + kh;
            const uint4 raw0 = *(const uint4*)&W1t[gb];
            const uint4 raw1 = *(const uint4*)&W1t[gb + 8];
            *(uint4*)&Bs[row][kh]     = raw0;
            *(uint4*)&Bs[row][kh + 8] = raw1;
        }
        __syncthreads();

        short8 af[4], bf[4];
        #pragma unroll
        for (int i = 0; i < 4; ++i)
            af[i] = *(const short8*)&As[wm * 64 + i * 16 + col][quad * 8];
        #pragma unroll
        for (int j = 0; j < 4; ++j)
            bf[j] = *(const short8*)&Bs[wn * 64 + j * 16 + col][quad * 8];
        #pragma unroll
        for (int i = 0; i < 4; ++i)
            #pragma unroll
            for (int j = 0; j < 4; ++j)
                acc[i][j] = __builtin_amdgcn_mfma_f32_16x16x32_bf16(af[i], bf[j], acc[i][j], 0, 0, 0);
        __syncthreads();
    }

    #pragma unroll
    for (int i = 0; i < 4; ++i) {
        #pragma unroll
        for (int reg = 0; reg < 4; ++reg) {
            const int gm = m0 + wm * 64 + i * 16 + quad * 4 + reg;
            if (gm < NNODES) {
                #pragma unroll
                for (int j = 0; j < 4; ++j) {
                    const int gc = n0 + wn * 64 + j * 16 + col;
                    h1[(size_t)gm * HD + gc] = f2bf(acc[i][j][reg]);
                }
            }
        }
    }
}

// ---------------- per-node attention scores for layer 1 ----------------------
__global__ __launch_bounds__(256) void al1_kernel(const unsigned short* __restrict__ h1,
                                                  const float* __restrict__ a_src,
                                                  const float* __restrict__ a_dst,
                                                  float* __restrict__ al_s,
                                                  float* __restrict__ al_d) {
    const int node = (blockIdx.x * 256 + threadIdx.x) >> 6;
    const int lane = threadIdx.x & 63;
    const ushort4 hb = *(const ushort4*)&h1[(size_t)node * HD + lane * 4];
    const float4 sv = *(const float4*)&a_src[lane * 4];
    const float4 dv = *(const float4*)&a_dst[lane * 4];
    const float h0 = bf2f(hb.x), h1v = bf2f(hb.y), h2v = bf2f(hb.z), h3 = bf2f(hb.w);
    float ps = h0 * sv.x + h1v * sv.y + h2v * sv.z + h3 * sv.w;
    float pd = h0 * dv.x + h1v * dv.y + h2v * dv.z + h3 * dv.w;
    #pragma unroll
    for (int off = 1; off < 16; off <<= 1) {
        ps += __shfl_xor(ps, off);
        pd += __shfl_xor(pd, off);
    }
    if ((lane & 15) == 0) {
        al_s[node * HEADS + (lane >> 4)] = ps;
        al_d[node * HEADS + (lane >> 4)] = pd;
    }
}

// ---------------- CSR build --------------------------------------------------
__global__ void deg_kernel(const int* __restrict__ ei, int E, int* __restrict__ deg) {
    const int e = blockIdx.x * 256 + threadIdx.x;
    if (e < E) atomicAdd(&deg[ei[E + e]], 1);
}

__global__ __launch_bounds__(1024) void scan_kernel(const int* __restrict__ deg,
                                                    int* __restrict__ offsets) {
    __shared__ int sums[1024];
    const int t = threadIdx.x;
    const int CH = (NNODES + 1023) / 1024;  // 49
    const int lo = t * CH;
    const int hi = min(lo + CH, NNODES);
    int s = 0;
    for (int i = lo; i < hi; ++i) s += deg[i];
    sums[t] = s;
    __syncthreads();
    for (int off = 1; off < 1024; off <<= 1) {
        int v = 0;
        if (t >= off) v = sums[t - off];
        __syncthreads();
        if (t >= off) sums[t] += v;
        __syncthreads();
    }
    int run = (t > 0) ? sums[t - 1] : 0;
    for (int i = lo; i < hi; ++i) {
        offsets[i] = run;
        run += deg[i];
    }
    if (t == 1023) offsets[NNODES] = sums[1023];
}

__global__ void scatter_kernel(const int* __restrict__ ei, int E,
                               const int* __restrict__ offsets,
                               int* __restrict__ cursor,
                               int* __restrict__ csr_src) {
    const int e = blockIdx.x * 256 + threadIdx.x;
    if (e < E) {
        const int dst = ei[E + e];
        const int src = ei[e];
        const int pos = offsets[dst] + atomicAdd(&cursor[dst], 1);
        csr_src[pos] = src;
    }
}

// ---------------- layer-1 aggregation: dual-stream pipelined online softmax --
__global__ __launch_bounds__(256) void agg1_kernel(const unsigned short* __restrict__ h1,
                                                   const float* __restrict__ al_s,
                                                   const float* __restrict__ al_d,
                                                   const int* __restrict__ offsets,
                                                   const int* __restrict__ csr_src,
                                                   const float* __restrict__ b1,
                                                   unsigned short* __restrict__ h_act) {
    const int node = (blockIdx.x * 256 + threadIdx.x) >> 6;
    const int lane = threadIdx.x & 63;
    const int h = lane >> 4;
    const float ad = al_d[node * HEADS + h];
    const int start = offsets[node];
    const int end = offsets[node + 1];
    const int last = end - 1;

    float mA = -1e30f, sA = 0.f, mB = -1e30f, sB = 0.f;
    float4 aA = make_float4(0.f, 0.f, 0.f, 0.f);
    float4 aB = make_float4(0.f, 0.f, 0.f, 0.f);

#define ROW1(s_) (*(const ushort4*)&h1[(size_t)(s_) * HD + lane * 4])
#define PROC1(sc_, v_, m_, s_, a_)                        \
    {                                                     \
        float e_ = sc_ + ad;                              \
        e_ = e_ > 0.f ? e_ : NEG_SLOPE * e_;              \
        const float nm_ = fmaxf(m_, e_);                  \
        const float scl_ = __expf(m_ - nm_);              \
        const float p_ = __expf(e_ - nm_);                \
        m_ = nm_;                                         \
        s_ = s_ * scl_ + p_;                              \
        a_.x = a_.x * scl_ + p_ * bf2f(v_.x);             \
        a_.y = a_.y * scl_ + p_ * bf2f(v_.y);             \
        a_.z = a_.z * scl_ + p_ * bf2f(v_.z);             \
        a_.w = a_.w * scl_ + p_ * bf2f(v_.w);             \
    }

    int srcA = csr_src[start];
    int srcB = csr_src[min(start + 1, last)];
    float scA = al_s[srcA * HEADS + h];
    float scB = (start + 1 < end) ? al_s[srcB * HEADS + h] : -__builtin_inff();
    ushort4 vA = ROW1(srcA);
    ushort4 vB = ROW1(srcB);

    for (int i = start; i < end; i += 2) {
        const int j = i + 2;
        const int nsrcA = csr_src[min(j, last)];
        const int nsrcB = csr_src[min(j + 1, last)];
        const float nscA = (j < end) ? al_s[nsrcA * HEADS + h] : -__builtin_inff();
        const float nscB = (j + 1 < end) ? al_s[nsrcB * HEADS + h] : -__builtin_inff();
        const ushort4 nvA = ROW1(nsrcA);
        const ushort4 nvB = ROW1(nsrcB);
        PROC1(scA, vA, mA, sA, aA);
        PROC1(scB, vB, mB, sB, aB);
        scA = nscA; vA = nvA; scB = nscB; vB = nvB;
    }
    const float M = fmaxf(mA, mB);
    const float eA = __expf(mA - M);
    const float eB = __expf(mB - M);
    const float s = sA * eA + sB * eB;
    float4 acc;
    acc.x = aA.x * eA + aB.x * eB;
    acc.y = aA.y * eA + aB.y * eB;
    acc.z = aA.z * eA + aB.z * eB;
    acc.w = aA.w * eA + aB.w * eB;

    const float inv = 1.f / (s + 1e-16f);
    const float4 bb = *(const float4*)&b1[lane * 4];
    float4 o;
    o.x = acc.x * inv + bb.x;
    o.y = acc.y * inv + bb.y;
    o.z = acc.z * inv + bb.z;
    o.w = acc.w * inv + bb.w;
    o.x = o.x > 0.f ? o.x : expm1f(o.x);
    o.y = o.y > 0.f ? o.y : expm1f(o.y);
    o.z = o.z > 0.f ? o.z : expm1f(o.z);
    o.w = o.w > 0.f ? o.w : expm1f(o.w);
    ushort4 ob;
    ob.x = f2bf(o.x); ob.y = f2bf(o.y); ob.z = f2bf(o.z); ob.w = f2bf(o.w);
    *(ushort4*)&h_act[(size_t)node * HD + lane * 4] = ob;
#undef ROW1
#undef PROC1
}

// ---------------- GEMM2 via MFMA: h2[N,40] = h_act[N,256] @ W2 + score dots --
// A-frags straight from global (quads cover full 64B lines); B staged in LDS.
#define G2M 64          // nodes per block (16 per wave)
#define BSTRIDE 264     // bf16 row stride for Bt: (addr/16)%8 = (n+quad)%8 -> even spread

__global__ __launch_bounds__(256) void gemm2_kernel(const unsigned short* __restrict__ h_act,
                                                    const unsigned short* __restrict__ W2t,
                                                    const float* __restrict__ a_s2,
                                                    const float* __restrict__ a_d2,
                                                    unsigned short* __restrict__ h2,
                                                    float* __restrict__ al_s,
                                                    float* __restrict__ al_d) {
    __shared__ unsigned short Bt[NCLSP][BSTRIDE];  // 25.3 KB
    const int tid = threadIdx.x;
    const int wave = tid >> 6;
    const int lane = tid & 63;
    const int quad = lane >> 4;
    const int col = lane & 15;
    const int m0 = blockIdx.x * G2M;

    // stage W2t[48][256] -> Bt (6 chunks of 8 bf16 per thread)
    #pragma unroll
    for (int it = 0; it < 6; ++it) {
        const int ch = it * 256 + tid;        // 0..1535
        const int n = ch >> 5;
        const int c8 = (ch & 31) * 8;
        *(uint4*)&Bt[n][c8] = *(const uint4*)&W2t[(size_t)n * HD + c8];
    }

    // A fragments: 16 rows per wave, K=256 in 8 steps of 32
    const int rowm = m0 + wave * 16 + col;    // A operand: m = lane&15
    const int arow = min(rowm, NNODES - 1);
    short8 af[8];
    #pragma unroll
    for (int ks = 0; ks < 8; ++ks)
        af[ks] = *(const short8*)&h_act[(size_t)arow * HD + ks * 32 + quad * 8];

    __syncthreads();

    f32x4 acc[3] = {};
    #pragma unroll
    for (int j = 0; j < 3; ++j) {
        #pragma unroll
        for (int ks = 0; ks < 8; ++ks) {
            const short8 bfr = *(const short8*)&Bt[j * 16 + col][ks * 32 + quad * 8];
            acc[j] = __builtin_amdgcn_mfma_f32_16x16x32_bf16(af[ks], bfr, acc[j], 0, 0, 0);
        }
    }

    // epilogue: D row = quad*4+reg (node), col c = j*16 + (lane&15)
    float ps[4] = {0.f, 0.f, 0.f, 0.f};
    float pd[4] = {0.f, 0.f, 0.f, 0.f};
    #pragma unroll
    for (int j = 0; j < 3; ++j) {
        const int c = j * 16 + col;
        const bool cv = c < NCLS;
        const float asc = cv ? a_s2[c] : 0.f;
        const float adc = cv ? a_d2[c] : 0.f;
        #pragma unroll
        for (int reg = 0; reg < 4; ++reg) {
            const float v = acc[j][reg];
            ps[reg] += v * asc;
            pd[reg] += v * adc;
            const int node = m0 + wave * 16 + quad * 4 + reg;
            if (cv && node < NNODES)
                h2[(size_t)node * NCLS + c] = f2bf(v);
        }
    }
    // reduce score dots across the 16 lanes of each quad
    #pragma unroll
    for (int reg = 0; reg < 4; ++reg) {
        #pragma unroll
        for (int off = 1; off < 16; off <<= 1) {
            ps[reg] += __shfl_xor(ps[reg], off);
            pd[reg] += __shfl_xor(pd[reg], off);
        }
    }
    if (col == 0) {
        #pragma unroll
        for (int reg = 0; reg < 4; ++reg) {
            const int node = m0 + wave * 16 + quad * 4 + reg;
            if (node < NNODES) {
                al_s[node] = ps[reg];
                al_d[node] = pd[reg];
            }
        }
    }
}

// ---------------- layer-2 aggregation: dual-stream pipelined + log_softmax ---
__global__ __launch_bounds__(256) void agg2_kernel(const unsigned short* __restrict__ h2,
                                                   const float* __restrict__ al_s,
                                                   const float* __restrict__ al_d,
                                                   const int* __restrict__ offsets,
                                                   const int* __restrict__ csr_src,
                                                   const float* __restrict__ b2,
                                                   float* __restrict__ out) {
    const int node = (blockIdx.x * 256 + threadIdx.x) >> 6;
    const int lane = threadIdx.x & 63;
    const int c = lane < NCLS ? lane : NCLS - 1;
    const float ad = al_d[node];
    const int start = offsets[node];
    const int end = offsets[node + 1];
    const int last = end - 1;

    float mA = -1e30f, sA = 0.f, accA = 0.f;
    float mB = -1e30f, sB = 0.f, accB = 0.f;

#define PROC2(sc_, v_, m_, s_, a_)                        \
    {                                                     \
        float e_ = sc_ + ad;                              \
        e_ = e_ > 0.f ? e_ : NEG_SLOPE * e_;              \
        const float nm_ = fmaxf(m_, e_);                  \
        const float scl_ = __expf(m_ - nm_);              \
        const float p_ = __expf(e_ - nm_);                \
        m_ = nm_;                                         \
        s_ = s_ * scl_ + p_;                              \
        a_ = a_ * scl_ + p_ * v_;                         \
    }

    int srcA = csr_src[start];
    int srcB = csr_src[min(start + 1, last)];
    float scA = al_s[srcA];
    float scB = (start + 1 < end) ? al_s[srcB] : -__builtin_inff();
    float vA = bf2f(h2[(size_t)srcA * NCLS + c]);
    float vB = bf2f(h2[(size_t)srcB * NCLS + c]);

    for (int i = start; i < end; i += 2) {
        const int j = i + 2;
        const int nsrcA = csr_src[min(j, last)];
        const int nsrcB = csr_src[min(j + 1, last)];
        const float nscA = (j < end) ? al_s[nsrcA] : -__builtin_inff();
        const float nscB = (j + 1 < end) ? al_s[nsrcB] : -__builtin_inff();
        const float nvA = bf2f(h2[(size_t)nsrcA * NCLS + c]);
        const float nvB = bf2f(h2[(size_t)nsrcB * NCLS + c]);
        PROC2(scA, vA, mA, sA, accA);
        PROC2(scB, vB, mB, sB, accB);
        scA = nscA; vA = nvA; scB = nscB; vB = nvB;
    }
    const float M = fmaxf(mA, mB);
    const float eA = __expf(mA - M);
    const float eB = __expf(mB - M);
    const float s = sA * eA + sB * eB;
    const float acc = accA * eA + accB * eB;
#undef PROC2

    float o = acc / (s + 1e-16f) + b2[c];
    float mx = (lane < NCLS) ? o : -1e30f;
    #pragma unroll
    for (int off = 1; off < 64; off <<= 1) mx = fmaxf(mx, __shfl_xor(mx, off));
    float ex = (lane < NCLS) ? __expf(o - mx) : 0.f;
    #pragma unroll
    for (int off = 1; off < 64; off <<= 1) ex += __shfl_xor(ex, off);
    const float res = o - mx - logf(ex);
    if (lane < NCLS) out[(size_t)node * NCLS + lane] = res;
}

// ---------------- launch -----------------------------------------------------
extern "C" void kernel_launch(void* const* d_in, const int* in_sizes, int n_in,
                              void* d_out, int out_size, void* d_ws, size_t ws_size,
                              hipStream_t stream) {
    const float* x      = (const float*)d_in[0];
    const int*   ei     = (const int*)d_in[1];
    const float* W1     = (const float*)d_in[2];
    const float* a_src1 = (const float*)d_in[3];
    const float* a_dst1 = (const float*)d_in[4];
    const float* b1     = (const float*)d_in[5];
    const float* W2     = (const float*)d_in[6];
    const float* a_src2 = (const float*)d_in[7];
    const float* a_dst2 = (const float*)d_in[8];
    const float* b2     = (const float*)d_in[9];
    float* out = (float*)d_out;
    const int E = in_sizes[1] / 2;

    char* ws = (char*)d_ws;
    size_t off = 0;
    auto alloc = [&](size_t bytes) -> char* {
        char* p = ws + off;
        off += (bytes + 255) & ~(size_t)255;
        return p;
    };
    unsigned short* W1t   = (unsigned short*)alloc((size_t)FIN * HD * 2);
    unsigned short* W2t   = (unsigned short*)alloc((size_t)NCLSP * HD * 2);
    unsigned short* h1    = (unsigned short*)alloc((size_t)NNODES * HD * 2);
    unsigned short* h_act = (unsigned short*)alloc((size_t)NNODES * HD * 2);
    unsigned short* h2    = (unsigned short*)alloc((size_t)NNODES * NCLS * 2);
    float* al_s1  = (float*)alloc((size_t)NNODES * HEADS * 4);
    float* al_d1  = (float*)alloc((size_t)NNODES * HEADS * 4);
    float* al_s2  = (float*)alloc((size_t)NNODES * 4);
    float* al_d2  = (float*)alloc((size_t)NNODES * 4);
    int*   deg    = (int*)alloc((size_t)NNODES * 4);
    int*   offs   = (int*)alloc((size_t)(NNODES + 1) * 4);
    int*   cursor = (int*)alloc((size_t)NNODES * 4);
    int*   csrsrc = (int*)alloc((size_t)E * 4);

    hipMemsetAsync(deg, 0, (size_t)NNODES * 4, stream);
    hipMemsetAsync(cursor, 0, (size_t)NNODES * 4, stream);

    const int eb = (E + 255) / 256;
    w1t_kernel<<<FIN * HD / 256, 256, 0, stream>>>(W1, W1t);
    w2t_kernel<<<NCLSP, 256, 0, stream>>>(W2, W2t);
    deg_kernel<<<eb, 256, 0, stream>>>(ei, E, deg);
    scan_kernel<<<1, 1024, 0, stream>>>(deg, offs);
    scatter_kernel<<<eb, 256, 0, stream>>>(ei, E, offs, cursor, csrsrc);

    gemm1_kernel<<<dim3((NNODES + BM - 1) / BM, HD / BN), 256, 0, stream>>>(x, W1t, h1);
    al1_kernel<<<NNODES / 4, 256, 0, stream>>>(h1, a_src1, a_dst1, al_s1, al_d1);
    agg1_kernel<<<NNODES / 4, 256, 0, stream>>>(h1, al_s1, al_d1, offs, csrsrc, b1, h_act);
    gemm2_kernel<<<(NNODES + G2M - 1) / G2M, 256, 0, stream>>>(h_act, W2t, a_src2, a_dst2, h2, al_s2, al_d2);
    agg2_kernel<<<NNODES / 4, 256, 0, stream>>>(h2, al_s2, al_d2, offs, csrsrc, b2, out);
}

// Round 6
// 544.829 us; speedup vs baseline: 1.4781x; 1.0037x over previous
//
#include <hip/hip_runtime.h>
#include <math.h>

#define NNODES 50000
#define FIN 512
#define HID 64
#define HEADS 4
#define HD (HEADS * HID)   // 256
#define NCLS 40
#define NCLSP 48           // padded to 3x16 for MFMA n-tiles
#define NEG_SLOPE 0.2f

typedef __attribute__((ext_vector_type(8))) short short8;
typedef __attribute__((ext_vector_type(4))) float f32x4;

static __device__ inline unsigned short f2bf(float f) {
    unsigned int u = __builtin_bit_cast(unsigned int, f);
    unsigned int r = (u + 0x7FFFu + ((u >> 16) & 1u)) >> 16;
    return (unsigned short)r;
}
static __device__ inline float bf2f(unsigned short b) {
    return __builtin_bit_cast(float, (unsigned int)b << 16);
}

// ---------------- W1 cast+transpose: W1[512,256] fp32 -> W1t[256,512] bf16 ---
__global__ __launch_bounds__(256) void w1t_kernel(const float* __restrict__ W1,
                                                  unsigned short* __restrict__ W1t) {
    const int idx = blockIdx.x * 256 + threadIdx.x;
    const int k = idx >> 8;          // 0..511
    const int n = idx & 255;         // 0..255
    W1t[n * FIN + k] = f2bf(W1[idx]);
}

// ---------------- W2 cast+transpose: W2[256,40] fp32 -> W2t[48][256] bf16 ----
__global__ __launch_bounds__(256) void w2t_kernel(const float* __restrict__ W2,
                                                  unsigned short* __restrict__ W2t) {
    const int idx = blockIdx.x * 256 + threadIdx.x;  // 48 blocks
    const int n = idx >> 8;          // 0..47
    const int k = idx & 255;         // 0..255
    W2t[n * HD + k] = (n < NCLS) ? f2bf(W2[k * NCLS + n]) : (unsigned short)0;
}

// ---------------- GEMM1: h1[N,256](bf16) = x[N,512] @ W1[512,256] via MFMA ---
// Latency-oriented: BK=64 (8 iters), register-prefetch double buffer, BN=64
// (1564 blocks). Staging loads for tile k+1 issue before tile k's MFMA phase.
#define BM 128
#define BN 64
#define BK 64
#define AST 72   // padded bf16 row stride (144 B): rows step 4 banks -> 2-way max

__global__ __launch_bounds__(256) void gemm1_kernel(const float* __restrict__ x,
                                                    const unsigned short* __restrict__ W1t,
                                                    unsigned short* __restrict__ h1) {
    __shared__ unsigned short As[BM][AST];  // 18.4 KB
    __shared__ unsigned short Bs[BN][AST];  // 9.2 KB
    const int m0 = blockIdx.x * BM;
    const int n0 = blockIdx.y * BN;
    const int tid = threadIdx.x;
    const int wave = tid >> 6;
    const int lane = tid & 63;
    const int wm = wave >> 1;        // 0..1 -> 64-row half
    const int wn = wave & 1;         // 0..1 -> 32-col half
    const int quad = lane >> 4;
    const int col = lane & 15;

    const int arow = tid >> 4;       // 0..15
    const int acol = (tid & 15) * 4; // 0..60
    const int brow = tid >> 2;       // 0..63
    const int bcol = (tid & 3) * 16; // 0,16,32,48

    float4 aR[8];
    uint4  bR[2];

#define LOAD_TILE(k0_)                                                          \
    {                                                                           \
        _Pragma("unroll")                                                       \
        for (int it = 0; it < 8; ++it) {                                        \
            const int gm = m0 + it * 16 + arow;                                 \
            aR[it] = (gm < NNODES)                                              \
                ? *(const float4*)&x[(size_t)gm * FIN + (k0_) + acol]           \
                : make_float4(0.f, 0.f, 0.f, 0.f);                              \
        }                                                                       \
        const size_t gb = (size_t)(n0 + brow) * FIN + (k0_) + bcol;             \
        bR[0] = *(const uint4*)&W1t[gb];                                        \
        bR[1] = *(const uint4*)&W1t[gb + 8];                                    \
    }

#define STORE_TILE()                                                            \
    {                                                                           \
        _Pragma("unroll")                                                       \
        for (int it = 0; it < 8; ++it) {                                        \
            ushort4 p;                                                          \
            p.x = f2bf(aR[it].x); p.y = f2bf(aR[it].y);                         \
            p.z = f2bf(aR[it].z); p.w = f2bf(aR[it].w);                         \
            *(ushort4*)&As[it * 16 + arow][acol] = p;                           \
        }                                                                       \
        *(uint4*)&Bs[brow][bcol]     = bR[0];                                   \
        *(uint4*)&Bs[brow][bcol + 8] = bR[1];                                   \
    }

    f32x4 acc[4][2] = {};

    LOAD_TILE(0)
    STORE_TILE()
    __syncthreads();

    for (int kt = 0; kt < 8; ++kt) {
        if (kt < 7) LOAD_TILE((kt + 1) * BK)   // in flight across MFMA phase
        #pragma unroll
        for (int ks = 0; ks < 2; ++ks) {
            short8 af[4], bf[2];
            #pragma unroll
            for (int i = 0; i < 4; ++i)
                af[i] = *(const short8*)&As[wm * 64 + i * 16 + col][ks * 32 + quad * 8];
            #pragma unroll
            for (int j = 0; j < 2; ++j)
                bf[j] = *(const short8*)&Bs[wn * 32 + j * 16 + col][ks * 32 + quad * 8];
            #pragma unroll
            for (int i = 0; i < 4; ++i)
                #pragma unroll
                for (int j = 0; j < 2; ++j)
                    acc[i][j] = __builtin_amdgcn_mfma_f32_16x16x32_bf16(af[i], bf[j], acc[i][j], 0, 0, 0);
        }
        __syncthreads();
        if (kt < 7) {
            STORE_TILE()
            __syncthreads();
        }
    }
#undef LOAD_TILE
#undef STORE_TILE

    // epilogue: D row = quad*4 + reg, col = lane&15 (m89-verified layout)
    #pragma unroll
    for (int i = 0; i < 4; ++i) {
        #pragma unroll
        for (int reg = 0; reg < 4; ++reg) {
            const int gm = m0 + wm * 64 + i * 16 + quad * 4 + reg;
            if (gm < NNODES) {
                #pragma unroll
                for (int j = 0; j < 2; ++j) {
                    const int gc = n0 + wn * 32 + j * 16 + col;
                    h1[(size_t)gm * HD + gc] = f2bf(acc[i][j][reg]);
                }
            }
        }
    }
}

// ---------------- per-node attention scores for layer 1 ----------------------
__global__ __launch_bounds__(256) void al1_kernel(const unsigned short* __restrict__ h1,
                                                  const float* __restrict__ a_src,
                                                  const float* __restrict__ a_dst,
                                                  float* __restrict__ al_s,
                                                  float* __restrict__ al_d) {
    const int node = (blockIdx.x * 256 + threadIdx.x) >> 6;
    const int lane = threadIdx.x & 63;
    const ushort4 hb = *(const ushort4*)&h1[(size_t)node * HD + lane * 4];
    const float4 sv = *(const float4*)&a_src[lane * 4];
    const float4 dv = *(const float4*)&a_dst[lane * 4];
    const float h0 = bf2f(hb.x), h1v = bf2f(hb.y), h2v = bf2f(hb.z), h3 = bf2f(hb.w);
    float ps = h0 * sv.x + h1v * sv.y + h2v * sv.z + h3 * sv.w;
    float pd = h0 * dv.x + h1v * dv.y + h2v * dv.z + h3 * dv.w;
    #pragma unroll
    for (int off = 1; off < 16; off <<= 1) {
        ps += __shfl_xor(ps, off);
        pd += __shfl_xor(pd, off);
    }
    if ((lane & 15) == 0) {
        al_s[node * HEADS + (lane >> 4)] = ps;
        al_d[node * HEADS + (lane >> 4)] = pd;
    }
}

// ---------------- CSR build --------------------------------------------------
__global__ void deg_kernel(const int* __restrict__ ei, int E, int* __restrict__ deg) {
    const int e = blockIdx.x * 256 + threadIdx.x;
    if (e < E) atomicAdd(&deg[ei[E + e]], 1);
}

__global__ __launch_bounds__(1024) void scan_kernel(const int* __restrict__ deg,
                                                    int* __restrict__ offsets) {
    __shared__ int sums[1024];
    const int t = threadIdx.x;
    const int CH = (NNODES + 1023) / 1024;  // 49
    const int lo = t * CH;
    const int hi = min(lo + CH, NNODES);
    int s = 0;
    for (int i = lo; i < hi; ++i) s += deg[i];
    sums[t] = s;
    __syncthreads();
    for (int off = 1; off < 1024; off <<= 1) {
        int v = 0;
        if (t >= off) v = sums[t - off];
        __syncthreads();
        if (t >= off) sums[t] += v;
        __syncthreads();
    }
    int run = (t > 0) ? sums[t - 1] : 0;
    for (int i = lo; i < hi; ++i) {
        offsets[i] = run;
        run += deg[i];
    }
    if (t == 1023) offsets[NNODES] = sums[1023];
}

__global__ void scatter_kernel(const int* __restrict__ ei, int E,
                               const int* __restrict__ offsets,
                               int* __restrict__ cursor,
                               int* __restrict__ csr_src) {
    const int e = blockIdx.x * 256 + threadIdx.x;
    if (e < E) {
        const int dst = ei[E + e];
        const int src = ei[e];
        const int pos = offsets[dst] + atomicAdd(&cursor[dst], 1);
        csr_src[pos] = src;
    }
}

// ---------------- layer-1 aggregation: dual-stream pipelined online softmax --
__global__ __launch_bounds__(256) void agg1_kernel(const unsigned short* __restrict__ h1,
                                                   const float* __restrict__ al_s,
                                                   const float* __restrict__ al_d,
                                                   const int* __restrict__ offsets,
                                                   const int* __restrict__ csr_src,
                                                   const float* __restrict__ b1,
                                                   unsigned short* __restrict__ h_act) {
    const int node = (blockIdx.x * 256 + threadIdx.x) >> 6;
    const int lane = threadIdx.x & 63;
    const int h = lane >> 4;
    const float ad = al_d[node * HEADS + h];
    const int start = offsets[node];
    const int end = offsets[node + 1];
    const int last = end - 1;

    float mA = -1e30f, sA = 0.f, mB = -1e30f, sB = 0.f;
    float4 aA = make_float4(0.f, 0.f, 0.f, 0.f);
    float4 aB = make_float4(0.f, 0.f, 0.f, 0.f);

#define ROW1(s_) (*(const ushort4*)&h1[(size_t)(s_) * HD + lane * 4])
#define PROC1(sc_, v_, m_, s_, a_)                        \
    {                                                     \
        float e_ = sc_ + ad;                              \
        e_ = e_ > 0.f ? e_ : NEG_SLOPE * e_;              \
        const float nm_ = fmaxf(m_, e_);                  \
        const float scl_ = __expf(m_ - nm_);              \
        const float p_ = __expf(e_ - nm_);                \
        m_ = nm_;                                         \
        s_ = s_ * scl_ + p_;                              \
        a_.x = a_.x * scl_ + p_ * bf2f(v_.x);             \
        a_.y = a_.y * scl_ + p_ * bf2f(v_.y);             \
        a_.z = a_.z * scl_ + p_ * bf2f(v_.z);             \
        a_.w = a_.w * scl_ + p_ * bf2f(v_.w);             \
    }

    int srcA = csr_src[start];
    int srcB = csr_src[min(start + 1, last)];
    float scA = al_s[srcA * HEADS + h];
    float scB = (start + 1 < end) ? al_s[srcB * HEADS + h] : -__builtin_inff();
    ushort4 vA = ROW1(srcA);
    ushort4 vB = ROW1(srcB);

    for (int i = start; i < end; i += 2) {
        const int j = i + 2;
        const int nsrcA = csr_src[min(j, last)];
        const int nsrcB = csr_src[min(j + 1, last)];
        const float nscA = (j < end) ? al_s[nsrcA * HEADS + h] : -__builtin_inff();
        const float nscB = (j + 1 < end) ? al_s[nsrcB * HEADS + h] : -__builtin_inff();
        const ushort4 nvA = ROW1(nsrcA);
        const ushort4 nvB = ROW1(nsrcB);
        PROC1(scA, vA, mA, sA, aA);
        PROC1(scB, vB, mB, sB, aB);
        scA = nscA; vA = nvA; scB = nscB; vB = nvB;
    }
    const float M = fmaxf(mA, mB);
    const float eA = __expf(mA - M);
    const float eB = __expf(mB - M);
    const float s = sA * eA + sB * eB;
    float4 acc;
    acc.x = aA.x * eA + aB.x * eB;
    acc.y = aA.y * eA + aB.y * eB;
    acc.z = aA.z * eA + aB.z * eB;
    acc.w = aA.w * eA + aB.w * eB;

    const float inv = 1.f / (s + 1e-16f);
    const float4 bb = *(const float4*)&b1[lane * 4];
    float4 o;
    o.x = acc.x * inv + bb.x;
    o.y = acc.y * inv + bb.y;
    o.z = acc.z * inv + bb.z;
    o.w = acc.w * inv + bb.w;
    o.x = o.x > 0.f ? o.x : expm1f(o.x);
    o.y = o.y > 0.f ? o.y : expm1f(o.y);
    o.z = o.z > 0.f ? o.z : expm1f(o.z);
    o.w = o.w > 0.f ? o.w : expm1f(o.w);
    ushort4 ob;
    ob.x = f2bf(o.x); ob.y = f2bf(o.y); ob.z = f2bf(o.z); ob.w = f2bf(o.w);
    *(ushort4*)&h_act[(size_t)node * HD + lane * 4] = ob;
#undef ROW1
#undef PROC1
}

// ---------------- GEMM2 via MFMA: h2[N,40] = h_act[N,256] @ W2 + score dots --
#define G2M 64          // nodes per block (16 per wave)
#define BSTRIDE 264

__global__ __launch_bounds__(256) void gemm2_kernel(const unsigned short* __restrict__ h_act,
                                                    const unsigned short* __restrict__ W2t,
                                                    const float* __restrict__ a_s2,
                                                    const float* __restrict__ a_d2,
                                                    unsigned short* __restrict__ h2,
                                                    float* __restrict__ al_s,
                                                    float* __restrict__ al_d) {
    __shared__ unsigned short Bt[NCLSP][BSTRIDE];  // 25.3 KB
    const int tid = threadIdx.x;
    const int wave = tid >> 6;
    const int lane = tid & 63;
    const int quad = lane >> 4;
    const int col = lane & 15;
    const int m0 = blockIdx.x * G2M;

    #pragma unroll
    for (int it = 0; it < 6; ++it) {
        const int ch = it * 256 + tid;        // 0..1535
        const int n = ch >> 5;
        const int c8 = (ch & 31) * 8;
        *(uint4*)&Bt[n][c8] = *(const uint4*)&W2t[(size_t)n * HD + c8];
    }

    const int rowm = m0 + wave * 16 + col;
    const int arow = min(rowm, NNODES - 1);
    short8 af[8];
    #pragma unroll
    for (int ks = 0; ks < 8; ++ks)
        af[ks] = *(const short8*)&h_act[(size_t)arow * HD + ks * 32 + quad * 8];

    __syncthreads();

    f32x4 acc[3] = {};
    #pragma unroll
    for (int j = 0; j < 3; ++j) {
        #pragma unroll
        for (int ks = 0; ks < 8; ++ks) {
            const short8 bfr = *(const short8*)&Bt[j * 16 + col][ks * 32 + quad * 8];
            acc[j] = __builtin_amdgcn_mfma_f32_16x16x32_bf16(af[ks], bfr, acc[j], 0, 0, 0);
        }
    }

    float ps[4] = {0.f, 0.f, 0.f, 0.f};
    float pd[4] = {0.f, 0.f, 0.f, 0.f};
    #pragma unroll
    for (int j = 0; j < 3; ++j) {
        const int c = j * 16 + col;
        const bool cv = c < NCLS;
        const float asc = cv ? a_s2[c] : 0.f;
        const float adc = cv ? a_d2[c] : 0.f;
        #pragma unroll
        for (int reg = 0; reg < 4; ++reg) {
            const float v = acc[j][reg];
            ps[reg] += v * asc;
            pd[reg] += v * adc;
            const int node = m0 + wave * 16 + quad * 4 + reg;
            if (cv && node < NNODES)
                h2[(size_t)node * NCLS + c] = f2bf(v);
        }
    }
    #pragma unroll
    for (int reg = 0; reg < 4; ++reg) {
        #pragma unroll
        for (int off = 1; off < 16; off <<= 1) {
            ps[reg] += __shfl_xor(ps[reg], off);
            pd[reg] += __shfl_xor(pd[reg], off);
        }
    }
    if (col == 0) {
        #pragma unroll
        for (int reg = 0; reg < 4; ++reg) {
            const int node = m0 + wave * 16 + quad * 4 + reg;
            if (node < NNODES) {
                al_s[node] = ps[reg];
                al_d[node] = pd[reg];
            }
        }
    }
}

// ---------------- layer-2 aggregation: dual-stream pipelined + log_softmax ---
__global__ __launch_bounds__(256) void agg2_kernel(const unsigned short* __restrict__ h2,
                                                   const float* __restrict__ al_s,
                                                   const float* __restrict__ al_d,
                                                   const int* __restrict__ offsets,
                                                   const int* __restrict__ csr_src,
                                                   const float* __restrict__ b2,
                                                   float* __restrict__ out) {
    const int node = (blockIdx.x * 256 + threadIdx.x) >> 6;
    const int lane = threadIdx.x & 63;
    const int c = lane < NCLS ? lane : NCLS - 1;
    const float ad = al_d[node];
    const int start = offsets[node];
    const int end = offsets[node + 1];
    const int last = end - 1;

    float mA = -1e30f, sA = 0.f, accA = 0.f;
    float mB = -1e30f, sB = 0.f, accB = 0.f;

#define PROC2(sc_, v_, m_, s_, a_)                        \
    {                                                     \
        float e_ = sc_ + ad;                              \
        e_ = e_ > 0.f ? e_ : NEG_SLOPE * e_;              \
        const float nm_ = fmaxf(m_, e_);                  \
        const float scl_ = __expf(m_ - nm_);              \
        const float p_ = __expf(e_ - nm_);                \
        m_ = nm_;                                         \
        s_ = s_ * scl_ + p_;                              \
        a_ = a_ * scl_ + p_ * v_;                         \
    }

    int srcA = csr_src[start];
    int srcB = csr_src[min(start + 1, last)];
    float scA = al_s[srcA];
    float scB = (start + 1 < end) ? al_s[srcB] : -__builtin_inff();
    float vA = bf2f(h2[(size_t)srcA * NCLS + c]);
    float vB = bf2f(h2[(size_t)srcB * NCLS + c]);

    for (int i = start; i < end; i += 2) {
        const int j = i + 2;
        const int nsrcA = csr_src[min(j, last)];
        const int nsrcB = csr_src[min(j + 1, last)];
        const float nscA = (j < end) ? al_s[nsrcA] : -__builtin_inff();
        const float nscB = (j + 1 < end) ? al_s[nsrcB] : -__builtin_inff();
        const float nvA = bf2f(h2[(size_t)nsrcA * NCLS + c]);
        const float nvB = bf2f(h2[(size_t)nsrcB * NCLS + c]);
        PROC2(scA, vA, mA, sA, accA);
        PROC2(scB, vB, mB, sB, accB);
        scA = nscA; vA = nvA; scB = nscB; vB = nvB;
    }
    const float M = fmaxf(mA, mB);
    const float eA = __expf(mA - M);
    const float eB = __expf(mB - M);
    const float s = sA * eA + sB * eB;
    const float acc = accA * eA + accB * eB;
#undef PROC2

    float o = acc / (s + 1e-16f) + b2[c];
    float mx = (lane < NCLS) ? o : -1e30f;
    #pragma unroll
    for (int off = 1; off < 64; off <<= 1) mx = fmaxf(mx, __shfl_xor(mx, off));
    float ex = (lane < NCLS) ? __expf(o - mx) : 0.f;
    #pragma unroll
    for (int off = 1; off < 64; off <<= 1) ex += __shfl_xor(ex, off);
    const float res = o - mx - logf(ex);
    if (lane < NCLS) out[(size_t)node * NCLS + lane] = res;
}

// ---------------- launch -----------------------------------------------------
extern "C" void kernel_launch(void* const* d_in, const int* in_sizes, int n_in,
                              void* d_out, int out_size, void* d_ws, size_t ws_size,
                              hipStream_t stream) {
    const float* x      = (const float*)d_in[0];
    const int*   ei     = (const int*)d_in[1];
    const float* W1     = (const float*)d_in[2];
    const float* a_src1 = (const float*)d_in[3];
    const float* a_dst1 = (const float*)d_in[4];
    const float* b1     = (const float*)d_in[5];
    const float* W2     = (const float*)d_in[6];
    const float* a_src2 = (const float*)d_in[7];
    const float* a_dst2 = (const float*)d_in[8];
    const float* b2     = (const float*)d_in[9];
    float* out = (float*)d_out;
    const int E = in_sizes[1] / 2;

    char* ws = (char*)d_ws;
    size_t off = 0;
    auto alloc = [&](size_t bytes) -> char* {
        char* p = ws + off;
        off += (bytes + 255) & ~(size_t)255;
        return p;
    };
    unsigned short* W1t   = (unsigned short*)alloc((size_t)FIN * HD * 2);
    unsigned short* W2t   = (unsigned short*)alloc((size_t)NCLSP * HD * 2);
    unsigned short* h1    = (unsigned short*)alloc((size_t)NNODES * HD * 2);
    unsigned short* h_act = (unsigned short*)alloc((size_t)NNODES * HD * 2);
    unsigned short* h2    = (unsigned short*)alloc((size_t)NNODES * NCLS * 2);
    float* al_s1  = (float*)alloc((size_t)NNODES * HEADS * 4);
    float* al_d1  = (float*)alloc((size_t)NNODES * HEADS * 4);
    float* al_s2  = (float*)alloc((size_t)NNODES * 4);
    float* al_d2  = (float*)alloc((size_t)NNODES * 4);
    int*   deg    = (int*)alloc((size_t)NNODES * 4);
    int*   offs   = (int*)alloc((size_t)(NNODES + 1) * 4);
    int*   cursor = (int*)alloc((size_t)NNODES * 4);
    int*   csrsrc = (int*)alloc((size_t)E * 4);

    hipMemsetAsync(deg, 0, (size_t)NNODES * 4, stream);
    hipMemsetAsync(cursor, 0, (size_t)NNODES * 4, stream);

    const int eb = (E + 255) / 256;
    w1t_kernel<<<FIN * HD / 256, 256, 0, stream>>>(W1, W1t);
    w2t_kernel<<<NCLSP, 256, 0, stream>>>(W2, W2t);
    deg_kernel<<<eb, 256, 0, stream>>>(ei, E, deg);
    scan_kernel<<<1, 1024, 0, stream>>>(deg, offs);
    scatter_kernel<<<eb, 256, 0, stream>>>(ei, E, offs, cursor, csrsrc);

    gemm1_kernel<<<dim3((NNODES + BM - 1) / BM, HD / BN), 256, 0, stream>>>(x, W1t, h1);
    al1_kernel<<<NNODES / 4, 256, 0, stream>>>(h1, a_src1, a_dst1, al_s1, al_d1);
    agg1_kernel<<<NNODES / 4, 256, 0, stream>>>(h1, al_s1, al_d1, offs, csrsrc, b1, h_act);
    gemm2_kernel<<<(NNODES + G2M - 1) / G2M, 256, 0, stream>>>(h_act, W2t, a_src2, a_dst2, h2, al_s2, al_d2);
    agg2_kernel<<<NNODES / 4, 256, 0, stream>>>(h2, al_s2, al_d2, offs, csrsrc, b2, out);
}